// Round 13
// baseline (126.983 us; speedup 1.0000x reference)
//
#include <hip/hip_runtime.h>
#include <hip/hip_bf16.h>

// BPTT diagonal RNN: u = X @ B^T, h_t = lam*h_{t-1} + u_t (chunked scan).
// R13: hybrid GEMM, 128x256 tile, grid 512 (2 blocks/CU for cross-block
// latency hiding). A (X f32) reg-staged with fused cvt; B pre-converted bf16
// staged via global_load_lds (zero VALU). R7-proven granule swizzle both
// operands. pass1 fused into GEMM epilogue; carry fused into pass3.
// Launches: cvt_B, gemm_hyb2, pass3f.

#define TDIM 8192
#define HDIM 2048
#define BM 128
#define BN 256
#define BK 32
#define NIT (HDIM / BK)        // 64 iters
#define ASLOT 4096             // shorts per A slot (128*32)
#define BSLOT 8192             // shorts per B slot (256*32)
#define LCH 64                 // scan chunk length
#define GCH (TDIM / LCH)       // 128 chunks

#define BBF_BYTES (HDIM * HDIM * 2)   // 8 MB
#define E_BYTES   (GCH * HDIM * 4)    // 1 MB
#define WS_NEED   ((size_t)BBF_BYTES + E_BYTES)

typedef float f32x4 __attribute__((ext_vector_type(4)));
typedef short s16x4 __attribute__((ext_vector_type(4)));
typedef short s16x8 __attribute__((ext_vector_type(8)));

static __device__ __forceinline__ short f2bf(float f) {
  __bf16 b = (__bf16)f;                 // RNE f32->bf16
  return __builtin_bit_cast(short, b);
}

#define GL(gp, lp)                                                            \
  __builtin_amdgcn_global_load_lds(                                           \
      (const __attribute__((address_space(1))) void*)(gp),                    \
      (__attribute__((address_space(3))) void*)(lp), 16, 0, 0)

// ---------------- B: f32 -> bf16 (24 MB traffic, proven pattern) ------------
__global__ void cvt_B(const float* __restrict__ src, short* __restrict__ dst) {
  const int base = blockIdx.x * 1024;   // f32x4 items, 1024 blocks
  const int t = threadIdx.x;
  f32x4 v0 = *(const f32x4*)(src + (size_t)(base +   0 + t) * 4);
  f32x4 v1 = *(const f32x4*)(src + (size_t)(base + 256 + t) * 4);
  f32x4 v2 = *(const f32x4*)(src + (size_t)(base + 512 + t) * 4);
  f32x4 v3 = *(const f32x4*)(src + (size_t)(base + 768 + t) * 4);
#define STORE1(v_, off_) do {                                                 \
    s16x4 o;                                                                  \
    o[0] = f2bf(v_[0]); o[1] = f2bf(v_[1]);                                   \
    o[2] = f2bf(v_[2]); o[3] = f2bf(v_[3]);                                   \
    *(s16x4*)(dst + (size_t)(base + (off_) + t) * 4) = o;                     \
  } while (0)
  STORE1(v0, 0); STORE1(v1, 256); STORE1(v2, 512); STORE1(v3, 768);
#undef STORE1
}

// ---------------- hybrid GEMM + fused pass1 ---------------------------------
// 4 waves (2Mx2N): wave tile 64x128 (4m x 8n frags). 2 blocks/CU.
// LDS rows 32 shorts (64B) = 4 x 16B granules; phys = logical ^ ((row>>1)&3)
// (R7-measured 0-conflict). A: f32 loads -> cvt -> ds_write_b64; B: gload_lds.
__global__ __launch_bounds__(256, 2) void gemm_hyb2(
    const float* __restrict__ X, const short* __restrict__ Bb,
    const float* __restrict__ lam,
    float* __restrict__ U, float* __restrict__ e) {
  __shared__ __align__(16) short As[2][ASLOT];   // 16 KiB
  __shared__ __align__(16) short Bs[2][BSLOT];   // 32 KiB

  // XCD swizzle: nwg=512 (%8==0, bijective): XCD x -> tm in [x*8, x*8+8)
  const int wg  = blockIdx.x;
  const int swz = (wg & 7) * 64 + (wg >> 3);
  const int tm = swz >> 3;              // 0..63
  const int tn = swz & 7;               // 0..7
  const int row0 = tm * BM, col0 = tn * BN;

  const int tid  = threadIdx.x;
  const int lane = tid & 63;
  const int wid  = tid >> 6;
  const int wr = (wid >> 1) * 64;       // 2 m-groups (chunk q = wid>>1)
  const int wc = (wid & 1) * 128;       // 2 n-groups
  const int r16 = lane & 15;
  const int g4  = lane >> 4;            // k-granule 0..3

  // fragment read offsets: off = r*32 + (g4 ^ ((r>>1)&3))*8
  int offA[4], offB[8];
#pragma unroll
  for (int m = 0; m < 4; ++m) {
    const int r = wr + m * 16 + r16;
    offA[m] = r * 32 + ((g4 ^ ((r >> 1) & 3)) << 3);
  }
#pragma unroll
  for (int n = 0; n < 8; ++n) {
    const int r = wc + n * 16 + r16;
    offB[n] = r * 32 + ((g4 ^ ((r >> 1) & 3)) << 3);
  }

  // A staging: load c in 0..3: row = (tid>>3) + c*32, floats [(tid&7)*4, +4)
  // (8 lanes x 16B = 128B contiguous per row -> coalesced)
  const float* gA = X + (size_t)(row0 + (tid >> 3)) * HDIM + (tid & 7) * 4;
  // A ds_write_b64: rc=(tid>>3)+c*32, g=(tid&7)>>1, half=tid&1,
  // phys = g ^ ((rc>>1)&3) = g ^ ((tid>>4)&3)  [c*32 drops out]
  const int offWbase = (((((tid & 7) >> 1) ^ ((tid >> 4) & 3)) << 3) + (tid & 1) * 4)
                       + (tid >> 3) * 32;

  // B staging via gload_lds: c in 0..3: unit u = c*256+tid -> LDS u*16B
  // (row=u>>2, phys=tid&3); source logical granule = (tid&3) ^ ((tid>>3)&3)
  const int sgB = (tid & 3) ^ ((tid >> 3) & 3);
  const short* gB = Bb + (size_t)(col0 + (tid >> 2)) * HDIM + sgB * 8;

#define ISSUE_A(dst, t_) do {                                                 \
    _Pragma("unroll") for (int c = 0; c < 4; ++c)                             \
      dst[c] = *(const f32x4*)(gA + (size_t)c * 32 * HDIM + (t_) * BK);       \
  } while (0)

#define CVTWR_A(arr, sl) do {                                                 \
    _Pragma("unroll") for (int c = 0; c < 4; ++c) {                           \
      s16x4 v;                                                                \
      v[0] = f2bf(arr[c][0]); v[1] = f2bf(arr[c][1]);                         \
      v[2] = f2bf(arr[c][2]); v[3] = f2bf(arr[c][3]);                         \
      *(s16x4*)&As[sl][offWbase + c * 32 * 32] = v;                           \
    }                                                                         \
  } while (0)

#define GLOADB(sl, t_) do {                                                   \
    _Pragma("unroll") for (int c = 0; c < 4; ++c)                             \
      GL(gB + (size_t)c * 64 * HDIM + (t_) * BK,                              \
         &Bs[sl][(c * 256 + tid) * 8]);                                       \
  } while (0)

#define PHASE(sl) do {                                                        \
    s16x8 af[4], bfv[8];                                                      \
    _Pragma("unroll") for (int m = 0; m < 4; ++m)                             \
      af[m] = *(const s16x8*)&As[sl][offA[m]];                                \
    _Pragma("unroll") for (int n = 0; n < 8; ++n)                             \
      bfv[n] = *(const s16x8*)&Bs[sl][offB[n]];                               \
    __builtin_amdgcn_s_setprio(1);                                            \
    _Pragma("unroll") for (int m = 0; m < 4; ++m)                             \
      _Pragma("unroll") for (int n = 0; n < 8; ++n)                           \
        acc[m][n] = __builtin_amdgcn_mfma_f32_16x16x32_bf16(                  \
            af[m], bfv[n], acc[m][n], 0, 0, 0);                               \
    __builtin_amdgcn_s_setprio(0);                                            \
  } while (0)

  f32x4 acc[4][8] = {};
  f32x4 ra[4];

  // prologue: tile 0 -> slot 0
  ISSUE_A(ra, 0);
  GLOADB(0, 0);
  CVTWR_A(ra, 0);
  __syncthreads();                      // drains vmcnt(0): B tile0 + A writes

#pragma unroll 2
  for (int j = 0; j < NIT - 1; ++j) {
    const int cur = j & 1;
    ISSUE_A(ra, j + 1);                 // 4 f32x4 loads (early issue)
    GLOADB(cur ^ 1, j + 1);             // 4 async gloads -> other slot
    PHASE(cur);                         // 12 ds_read + 32 MFMA (aging window)
    CVTWR_A(ra, cur ^ 1);               // consume-late
    __syncthreads();                    // next slot fully staged
  }
  PHASE((NIT - 1) & 1);

  // ---------------- epilogue 1: write U (C/D map verified R1-R12) -----------
  const int crow = row0 + wr + (g4 << 2);
  const int ccol = col0 + wc + r16;
#pragma unroll
  for (int m = 0; m < 4; ++m)
#pragma unroll
    for (int n = 0; n < 8; ++n)
#pragma unroll
      for (int j = 0; j < 4; ++j)
        U[(size_t)(crow + m * 16 + j) * HDIM + ccol + n * 16] = acc[m][n][j];

  // ---------------- epilogue 2: fused pass1 ---------------------------------
  // Wave tile = 64 rows = exactly one chunk (q = wid>>1).
  // e_j[c] = sum_{r=0..63} lam^(63-r) u_r
  //        = lam^{4(3-g4)} * Horner_m(lam^16, Horner_jj(lam, acc rows))
#pragma unroll
  for (int n = 0; n < 8; ++n) {
    const int c = ccol + n * 16;
    const float l  = lam[c];
    const float l2 = l * l;
    const float l4 = l2 * l2;
    const float l8 = l4 * l4;
    const float l16 = l8 * l8;
    float lg = 1.f;                     // lam^{4*(3-g4)}
    if (g4 < 3) lg = l4;
    if (g4 < 2) lg *= l4;
    if (g4 < 1) lg *= l4;
    float S = 0.f;
#pragma unroll
    for (int m = 0; m < 4; ++m) {
      const f32x4 a = acc[m][n];
      const float T = ((a[0] * l + a[1]) * l + a[2]) * l + a[3];
      S = S * l16 + T;
    }
    S *= lg;
    S += __shfl_xor(S, 16, 64);
    S += __shfl_xor(S, 32, 64);
    if (g4 == 0) {
      const int j = tm * 2 + (wid >> 1);   // global chunk index
      e[(size_t)j * HDIM + c] = S;
    }
  }

#undef ISSUE_A
#undef CVTWR_A
#undef GLOADB
#undef PHASE
}

// ---------------- pass3 with inline carry (reads e non-destructively) -------
__global__ void pass3f(float* __restrict__ U, const float* __restrict__ lam,
                       const float* __restrict__ e) {
  const int c = (blockIdx.y * 256 + threadIdx.x) * 4;
  const int j = blockIdx.x;
  const f32x4 l4 = *(const f32x4*)&lam[c];
  f32x4 p = l4;
#pragma unroll
  for (int i = 0; i < 6; ++i) p = p * p;   // lam^64
  f32x4 E = {0.f, 0.f, 0.f, 0.f};
  for (int jp = 0; jp < j; ++jp) {         // carry prefix (redundant, L2-hot)
    f32x4 ej = *(const f32x4*)&e[(size_t)jp * HDIM + c];
    E = p * E + ej;
  }
  float* up = U + (size_t)j * LCH * HDIM + c;
  f32x4 h = E;
#pragma unroll 4
  for (int t = 0; t < LCH; ++t) {
    f32x4 u4 = *(const f32x4*)up;
    h = l4 * h + u4;
    *(f32x4*)up = h;
    up += HDIM;
  }
}

// ---------------- fallback path (proven R1 pieces) --------------------------
__global__ __launch_bounds__(256, 2) void gemm_f32_fb(
    const float* __restrict__ X, const float* __restrict__ Bm,
    float* __restrict__ U) {
#define LDK 40
#define FBM 128
#define FBK 32
#define FNT (HDIM / FBK)
  __shared__ __align__(16) short As[2][FBM * LDK];
  __shared__ __align__(16) short Bs[2][FBM * LDK];
  const int wg  = blockIdx.x;
  const int cpx = (TDIM / FBM) * (HDIM / FBM) / 8;
  const int swz = (wg & 7) * cpx + (wg >> 3);
  const int tm = swz >> 4;
  const int tn = swz & 15;
  const int row0 = tm * FBM, col0 = tn * FBM;
  const int tid  = threadIdx.x;
  const int lane = tid & 63;
  const int wid  = tid >> 6;
  const int wr = (wid >> 1) * 64;
  const int wc = (wid & 1) * 64;
  const int srow = tid >> 2;
  const int sk   = (tid & 3) << 3;
  const float* gA  = X  + (size_t)(row0 + srow) * HDIM + sk;
  const float* gA2 = gA + 64 * HDIM;
  const float* gB  = Bm + (size_t)(col0 + srow) * HDIM + sk;
  const float* gB2 = gB + 64 * HDIM;
  f32x4 a00, a01, a10, a11, b00, b01, b10, b11;
#define LOADREG(kt) do {                                                      \
    const float* p;                                                           \
    p = gA  + (kt) * FBK; a00 = *(const f32x4*)p; a01 = *(const f32x4*)(p+4); \
    p = gA2 + (kt) * FBK; a10 = *(const f32x4*)p; a11 = *(const f32x4*)(p+4); \
    p = gB  + (kt) * FBK; b00 = *(const f32x4*)p; b01 = *(const f32x4*)(p+4); \
    p = gB2 + (kt) * FBK; b10 = *(const f32x4*)p; b11 = *(const f32x4*)(p+4); \
  } while (0)
#define CVT8(v, lo, hi) do {                                                  \
    v[0] = f2bf(lo[0]); v[1] = f2bf(lo[1]); v[2] = f2bf(lo[2]);               \
    v[3] = f2bf(lo[3]); v[4] = f2bf(hi[0]); v[5] = f2bf(hi[1]);               \
    v[6] = f2bf(hi[2]); v[7] = f2bf(hi[3]);                                   \
  } while (0)
#define DSWRITE(buf) do {                                                     \
    s16x8 v;                                                                  \
    CVT8(v, a00, a01); *(s16x8*)&As[buf][srow * LDK + sk] = v;                \
    CVT8(v, a10, a11); *(s16x8*)&As[buf][(srow + 64) * LDK + sk] = v;         \
    CVT8(v, b00, b01); *(s16x8*)&Bs[buf][srow * LDK + sk] = v;                \
    CVT8(v, b10, b11); *(s16x8*)&Bs[buf][(srow + 64) * LDK + sk] = v;         \
  } while (0)
  f32x4 acc[4][4] = {};
#define COMPUTE(buf) do {                                                     \
    const int r16_ = lane & 15;                                               \
    const int ks_  = (lane >> 4) * 8;                                         \
    s16x8 af[4], bfr[4];                                                      \
    _Pragma("unroll") for (int m = 0; m < 4; ++m)                             \
      af[m] = *(const s16x8*)&As[buf][(wr + m * 16 + r16_) * LDK + ks_];      \
    _Pragma("unroll") for (int n = 0; n < 4; ++n)                             \
      bfr[n] = *(const s16x8*)&Bs[buf][(wc + n * 16 + r16_) * LDK + ks_];     \
    _Pragma("unroll") for (int m = 0; m < 4; ++m)                             \
      _Pragma("unroll") for (int n = 0; n < 4; ++n)                           \
        acc[m][n] = __builtin_amdgcn_mfma_f32_16x16x32_bf16(                  \
            af[m], bfr[n], acc[m][n], 0, 0, 0);                               \
  } while (0)
  LOADREG(0);
  DSWRITE(0);
  __syncthreads();
#pragma unroll 2
  for (int kt = 0; kt < FNT; ++kt) {
    const int cur = kt & 1;
    if (kt + 1 < FNT) LOADREG(kt + 1);
    COMPUTE(cur);
    if (kt + 1 < FNT) DSWRITE(cur ^ 1);
    __syncthreads();
  }
  const int crow = wr + ((lane >> 4) << 2);
  const int ccol = wc + (lane & 15);
#pragma unroll
  for (int m = 0; m < 4; ++m)
#pragma unroll
    for (int n = 0; n < 4; ++n)
#pragma unroll
      for (int j = 0; j < 4; ++j)
        U[(size_t)(row0 + crow + m * 16 + j) * HDIM + (col0 + ccol + n * 16)] =
            acc[m][n][j];
#undef LOADREG
#undef CVT8
#undef DSWRITE
#undef COMPUTE
#undef LDK
#undef FBM
#undef FBK
#undef FNT
}

__global__ void scan_pass1(const float* __restrict__ U,
                           const float* __restrict__ lam,
                           float* __restrict__ e) {
  const int c = (blockIdx.y * 256 + threadIdx.x) * 4;
  const int j = blockIdx.x;
  const f32x4 l4 = *(const f32x4*)&lam[c];
  f32x4 h = {0.f, 0.f, 0.f, 0.f};
  const float* up = U + (size_t)j * LCH * HDIM + c;
#pragma unroll 4
  for (int t = 0; t < LCH; ++t) {
    f32x4 u4 = *(const f32x4*)up;
    h = l4 * h + u4;
    up += HDIM;
  }
  *(f32x4*)&e[(size_t)j * HDIM + c] = h;
}

extern "C" void kernel_launch(void* const* d_in, const int* in_sizes, int n_in,
                              void* d_out, int out_size, void* d_ws, size_t ws_size,
                              hipStream_t stream) {
  const float* X   = (const float*)d_in[0];
  const float* lam = (const float*)d_in[1];
  const float* Bm  = (const float*)d_in[2];
  float* U = (float*)d_out;              // u then h, in-place

  if (ws_size >= WS_NEED) {
    short* Bb = (short*)d_ws;
    float* e  = (float*)((char*)d_ws + BBF_BYTES);

    cvt_B<<<dim3(HDIM * HDIM / 4096), dim3(256), 0, stream>>>(Bm, Bb);
    gemm_hyb2<<<dim3((TDIM / BM) * (HDIM / BN)), dim3(256), 0, stream>>>(
        X, Bb, lam, U, e);
    pass3f<<<dim3(GCH, HDIM / 1024), dim3(256), 0, stream>>>(U, lam, e);
  } else {
    float* e = (float*)d_ws;
    gemm_f32_fb<<<dim3((TDIM / 128) * (HDIM / 128)), dim3(256), 0, stream>>>(
        X, Bm, U);
    scan_pass1<<<dim3(GCH, HDIM / 1024), dim3(256), 0, stream>>>(U, lam, e);
    pass3f<<<dim3(GCH, HDIM / 1024), dim3(256), 0, stream>>>(U, lam, e);
  }
}